// Round 15
// baseline (136.827 us; speedup 1.0000x reference)
//
#include <hip/hip_runtime.h>
#include <math.h>

#define B_    4
#define C_    19
#define H_    320
#define W_    320
#define HW_   (H_*W_)
#define CHW_  (C_*HW_)
#define NPIX_ (B_*HW_)
#define NEPS_ 256
#define BIGI_ (1<<20)
#define INF_  0x3fffffff
#define IGN_  255
#define REC_  20          // padded record stride (floats)

// Compile-time exact replica of the reference eps chain: e0=1e-5f, e_{k+1}=e_k*1.2f
struct EpsTab { float v[NEPS_]; };
static constexpr EpsTab make_eps() {
  EpsTab t{}; float e = 1e-5f;
  for (int k = 0; k < NEPS_; ++k) { t.v[k] = e; e = e * 1.2f; }
  return t;
}
__device__ __constant__ EpsTab EPS = make_eps();

// ---------------- reduction helper (nw full waves) ---------------------------
__device__ __forceinline__ void block_reduce_add_w(float v, float* out, int nw) {
  #pragma unroll
  for (int o = 32; o > 0; o >>= 1) v += __shfl_down(v, o);
  __shared__ float shr[8];
  int lane = threadIdx.x & 63, wid = threadIdx.x >> 6;
  if (lane == 0) shr[wid] = v;
  __syncthreads();
  if (threadIdx.x == 0) {
    float s = 0.f;
    for (int w = 0; w < nw; ++w) s += shr[w];
    atomicAdd(out, s);
  }
}

__device__ __forceinline__ int eps_bin(float kl, const float* et) {
  // #{k : e_k < kl}, log2 guess + exact correction (identical compares to ref)
  if (!(kl > 1e-5f)) return 0;
  int g = (int)((__log2f(kl) + 16.6096404f) * 3.8017840f);
  g = min(max(g, 0), NEPS_ - 1);
  while (g < NEPS_ && et[g] < kl) ++g;
  while (g > 0 && !(et[g - 1] < kl)) --g;
  return g;
}

// ---------------- K1: row distance transform + workspace init ---------------
__global__ __launch_bounds__(320) void k_rowdt(const int* __restrict__ tgt, int* __restrict__ Rt,
                                               int* __restrict__ hist, float* __restrict__ out) {
  int bid = blockIdx.x;                  // b*H_ + i
  int b = bid / H_, i = bid - b * H_;
  int j = threadIdx.x, lane = j & 63, wv = j >> 6;
  if (bid == 0) {
    if (j < 257) hist[j] = 0;
    if (j == 319) out[0] = 0.f;
  }
  bool hd = (i < H_ - 1);
  const int* trow = tgt + b * HW_ + i * W_;
  int t0 = trow[j];
  int t1 = hd ? trow[W_ + j] : t0;
  int t0r = (j < W_ - 1) ? trow[j + 1] : t0;
  bool bnd = (t0 == IGN_) || (t1 != t0) || (t0r != t0);
  int s = bnd ? 0 : BIGI_;
  int a = s - j, c = s + j;
  #pragma unroll
  for (int o = 1; o < 64; o <<= 1) {
    int v = __shfl_up(a, o);
    if (lane >= o) a = min(a, v);
    int w = __shfl_down(c, o);
    if (lane + o < 64) c = min(c, w);
  }
  __shared__ int wa[5], wc[5];
  if (lane == 63) wa[wv] = a;
  if (lane == 0)  wc[wv] = c;
  __syncthreads();
  #pragma unroll
  for (int w = 0; w < 5; ++w) {
    if (w < wv) a = min(a, wa[w]);
    if (w > wv) c = min(c, wc[w]);
  }
  Rt[(b * W_ + j) * H_ + i] = min(a + j, c - j);   // transposed store
}

// ---------------- K0: per-PAIR softmax/KL (f2b) + LDS-coalesced X/P stores --
// EXACT R14 version (measured ~31.5us; absmax 0.0).
__global__ __launch_bounds__(256) void k_soft(const float* __restrict__ sl, const int* __restrict__ tgt,
                                              float2* __restrict__ LS, float* __restrict__ kl_map,
                                              float* __restrict__ X, float* __restrict__ P,
                                              int* __restrict__ hist, float* __restrict__ out) {
  int tid = threadIdx.x;
  int t = blockIdx.x * 256 + tid;                // pair index, 0..NPIX_/2-1
  int b = t / (HW_ / 2), q = t - b * (HW_ / 2);
  int p = q * 2;                                 // pixel base (j even)
  int i = p / W_, j = p - i * W_;
  bool hd = (i < H_ - 1);
  bool hr1 = (j + 2 < W_);                       // pixel1 has a right neighbor
  __shared__ float et[NEPS_];
  __shared__ int sh[257];
  __shared__ float RS[256][41];                  // record staging (X, then P)
  et[tid] = EPS.v[tid];
  sh[tid] = 0;
  if (tid == 0) sh[256] = 0;

  const float* base = sl + (size_t)b * CHW_ + p;
  int2 t2 = *(const int2*)(tgt + b * HW_ + p);

  float x0s[C_], x1s[C_];                        // own logits stash (static idx)
  float se0=0.f,se1=0.f, E0=0.f,E1=0.f;
  float dD0=0.f,dD1=0.f, sB0=0.f,sB1=0.f;
  float dR0=0.f,dR1=0.f, sR1=0.f;
  float xt0=0.f,xt1=0.f;
  #pragma unroll
  for (int c0 = 0; c0 < C_; c0 += 5) {
    const int NB = (c0 + 5 <= C_) ? 5 : (C_ - c0);
    float2 xo[5], xd[5];
    float  xr[5];
    #pragma unroll
    for (int k = 0; k < NB; ++k) {
      const float* pc = base + (c0 + k) * HW_;
      xo[k] = *(const float2*)pc;
      xd[k] = hd ? *(const float2*)(pc + W_) : make_float2(0.f, 0.f);
      xr[k] = hr1 ? pc[2] : 0.f;
    }
    #pragma unroll
    for (int k = 0; k < NB; ++k) {
      int c = c0 + k;
      x0s[c] = xo[k].x; x1s[c] = xo[k].y;
      float e0 = __expf(xo[k].x), e1 = __expf(xo[k].y);
      se0 += e0; E0 += e0 * xo[k].x;
      se1 += e1; E1 += e1 * xo[k].y;
      dD0 += e0 * xd[k].x; dD1 += e1 * xd[k].y;
      sB0 += __expf(xd[k].x); sB1 += __expf(xd[k].y);
      dR0 += e0 * xo[k].y; dR1 += e1 * xr[k];
      sR1 += __expf(xr[k]);
      if (c == t2.x) xt0 = xo[k].x;
      if (c == t2.y) xt1 = xo[k].y;
    }
  }
  float lz0 = __logf(se0), lz1 = __logf(se1);
  float Sv0 = E0 / se0 - lz0, Sv1 = E1 / se1 - lz1;
  float nll = ((t2.x != IGN_) ? (lz0 - xt0) : 0.f) + ((t2.y != IGN_) ? (lz1 - xt1) : 0.f);
  float kl0 = hd ? (Sv0 - dD0 / se0 + __logf(sB0)) : 0.f;
  float kl1 = hd ? (Sv1 - dD1 / se1 + __logf(sB1)) : 0.f;
  kl0 += Sv0 - dR0 / se0 + lz1;
  if (hr1) kl1 += Sv1 - dR1 / se1 + __logf(sR1);

  // ---- X records via LDS coalescing ----
  #pragma unroll
  for (int c = 0; c < C_; ++c) { RS[tid][c] = x0s[c]; RS[tid][20 + c] = x1s[c]; }
  RS[tid][19] = 0.f; RS[tid][40] = 0.f;
  RS[tid][39] = 0.f;
  __syncthreads();
  {
    float* xb = X + (size_t)blockIdx.x * (256 * 2 * REC_);
    #pragma unroll
    for (int r = 0; r < 10; ++r) {
      int f4 = r * 256 + tid;                    // 0..2559
      int rec = f4 / 10, e0 = (f4 - rec * 10) * 4;
      float4 v = make_float4(RS[rec][e0], RS[rec][e0 + 1], RS[rec][e0 + 2], RS[rec][e0 + 3]);
      *(float4*)(xb + (size_t)f4 * 4) = v;       // rec*40+e0 == f4*4: linear, coalesced
    }
  }
  __syncthreads();
  // ---- P records via LDS coalescing (exp computed straight into LDS) ----
  #pragma unroll
  for (int c = 0; c < C_; ++c) {
    RS[tid][c]      = __expf(x0s[c] - lz0);      // same input bits as R13 -> same output
    RS[tid][20 + c] = __expf(x1s[c] - lz1);
  }
  RS[tid][19] = 0.f; RS[tid][39] = 0.f;
  __syncthreads();
  {
    float* pb = P + (size_t)blockIdx.x * (256 * 2 * REC_);
    #pragma unroll
    for (int r = 0; r < 10; ++r) {
      int f4 = r * 256 + tid;
      int rec = f4 / 10, e0 = (f4 - rec * 10) * 4;
      float4 v = make_float4(RS[rec][e0], RS[rec][e0 + 1], RS[rec][e0 + 2], RS[rec][e0 + 3]);
      *(float4*)(pb + (size_t)f4 * 4) = v;
    }
  }

  int gp = b * HW_ + p;
  LS[gp]     = make_float2(lz0, Sv0);
  LS[gp + 1] = make_float2(lz1, Sv1);
  *(float2*)(kl_map + gp) = make_float2(kl0, kl1);
  __syncthreads();                       // et/sh init + staging done
  atomicAdd(&sh[eps_bin(kl0, et)], 1);
  atomicAdd(&sh[eps_bin(kl1, et)], 1);
  __syncthreads();
  if (sh[tid]) atomicAdd(&hist[tid], sh[tid]);
  if (tid == 0 && sh[256]) atomicAdd(&hist[256], sh[256]);
  block_reduce_add_w(nll, out, 4);
}

// ---------------- K2: column combine + (block 0) eps selection --------------
__global__ __launch_bounds__(H_) void k_coldt(const int* __restrict__ Rt, int* __restrict__ dist,
                                              const int* __restrict__ hist, float* __restrict__ eps_sel) {
  int b = blockIdx.x / W_, j = blockIdx.x % W_, tid = threadIdx.x;
  __shared__ int lev[9][H_];
  lev[0][tid] = Rt[(b * W_ + j) * H_ + tid];
  int Ri = lev[0][tid];
  for (int l = 1; l <= 8; ++l) {
    int half = 1 << (l - 1);
    __syncthreads();
    int other = (tid + half < H_) ? lev[l - 1][tid + half] : INF_;
    lev[l][tid] = min(lev[l - 1][tid], other);
  }
  __syncthreads();
  int i0 = tid;
  auto feas = [&](int dd) -> bool {
    int lo = max(0, i0 - dd), hi = min(H_ - 1, i0 + dd);
    int len = hi - lo + 1;
    int l = 31 - __clz(len);
    int m = min(lev[l][lo], lev[l][hi - (1 << l) + 1]);
    return m <= dd;
  };
  int d;
  int hi = min(Ri, 512);                 // d <= R[i0]
  if (!feas(hi)) d = B_ + 1 + H_ + W_;   // no seed in image
  else {
    int lo = 0;
    while (lo < hi) { int mid = (lo + hi) >> 1; if (feas(mid)) hi = mid; else lo = mid + 1; }
    d = lo;
  }
  dist[(b * H_ + i0) * W_ + j] = d;
  // block 0: eps via suffix scan of hist (bins 1..256)
  if (blockIdx.x == 0) {
    __shared__ int g[256];
    __shared__ int bestk;
    if (tid < 256) g[tid] = hist[tid + 1];
    if (tid == 0) bestk = NEPS_ - 1;
    __syncthreads();
    #pragma unroll
    for (int ofs = 1; ofs < 256; ofs <<= 1) {
      int v = 0;
      if (tid < 256) v = g[tid] + ((tid + ofs < 256) ? g[tid + ofs] : 0);
      __syncthreads();
      if (tid < 256) g[tid] = v;
      __syncthreads();
    }
    if (tid < 256 && g[tid] <= 5120) atomicMin(&bestk, tid);
    __syncthreads();
    if (tid == 0) eps_sel[0] = EPS.v[bestk];
  }
}

// ---------------- K3: mask+direction+dterm + CE from LDS-staged P records ---
// R14's CE math verbatim, but the 8-neighbor P/LS gathers read a ONE-SHOT
// staged LDS halo instead of scattered global records (R14's measured 31.6us
// came from ~8x redundant re-reads thrashing L1: each halo record is read by
// up to 8 threads). Staging = perfectly linear float4 loads from the record
// array (unlike R9's failed strided-slices staging) -- 26KB P halo + 2.6KB LS
// halo per block, clamped indices (R9-validated clamp semantics). Own X stays
// a direct coalesced global read. All values bit-copies; dot/tree order
// unchanged -> absmax 0.0 invariant.
__global__ __launch_bounds__(256) void k_maskce(const float* __restrict__ X, const float* __restrict__ P,
                                                const float2* __restrict__ LS, const float* __restrict__ kl_map,
                                                const int* __restrict__ dist, const float* __restrict__ eps_sel,
                                                float* __restrict__ out) {
  const int nx9[9] = {1,-1,0,0,-1,1,-1,1,0};
  const int ny9[9] = {0,0,-1,1,1,1,-1,-1,0};
  int tid = threadIdx.x;
  int b = blockIdx.z;
  int i0 = blockIdx.y * 16, j0 = blockIdx.x * 16;
  float eps = eps_sel[0];
  __shared__ float kt[18][19];
  __shared__ int   dt_[18][19];
  __shared__ float Ph[324][REC_];        // P halo records (clamped), 25.9 KB
  __shared__ float2 LSh[324];            // LS halo (clamped)
  for (int e = tid; e < 324; e += 256) {
    int r = e / 18, cc = e - r * 18;
    int gi = i0 - 1 + r, gj = j0 - 1 + cc;
    bool in = (gi >= 0 && gi < H_ && gj >= 0 && gj < W_);
    int gidx = (b * H_ + gi) * W_ + gj;
    kt[r][cc]  = in ? kl_map[gidx] : -1e30f;
    dt_[r][cc] = in ? dist[gidx] : 100000;
    int gic = min(max(gi, 0), H_ - 1), gjc = min(max(gj, 0), W_ - 1);
    LSh[e] = LS[b * HW_ + gic * W_ + gjc];
  }
  for (int idx = tid; idx < 324 * 5; idx += 256) {
    int rec = idx / 5, f = idx - rec * 5;
    int r = rec / 18, cc = rec - r * 18;
    int gic = min(max(i0 - 1 + r, 0), H_ - 1);
    int gjc = min(max(j0 - 1 + cc, 0), W_ - 1);
    float4 v = *(const float4*)(P + (size_t)(b * HW_ + gic * W_ + gjc) * REC_ + f * 4);
    *(float4*)(&Ph[rec][f * 4]) = v;     // row = 80B, 16B-aligned
  }
  __syncthreads();
  int li = tid >> 4, lj = tid & 15;
  bool mask = false;
  #pragma unroll
  for (int dr = 0; dr < 3; ++dr)
    #pragma unroll
    for (int dc = 0; dc < 3; ++dc)
      mask |= (kt[li + dr][lj + dc] > eps);
  int best = INF_, dir = 0;
  #pragma unroll
  for (int k = 0; k < 9; ++k) {
    int r = dt_[li + 1 + nx9[k]][lj + 1 + ny9[k]];
    if (r < best) { best = r; dir = k; }
  }
  bool valid = mask && (dir != 8);
  float acc = 0.f;
  if (valid) {
    int i = i0 + li, j = j0 + lj;
    acc = fminf((float)dt_[li + 1][lj + 1], 20.f) * (1.f / 20.f);
    int label = min(dir, 7);
    int gp = b * HW_ + i * W_ + j;
    float lzc = LSh[(li + 1) * 18 + (lj + 1)].x;   // == LS[gp].x (interior, bit-copy)
    const float4* xo = (const float4*)(X + (size_t)gp * REC_);
    float4 a0 = xo[0], a1 = xo[1], a2 = xo[2], a3 = xo[3], a4 = xo[4];
    float kv0, kv1, kv2, kv3, kv4, kv5, kv6, kv7;
#define SLOTK(K, KV) { \
    int rn = (li + 1 + nx9[K]) * 18 + (lj + 1 + ny9[K]); \
    float2 lsn = LSh[rn]; \
    const float4* pn = (const float4*)(&Ph[rn][0]); \
    float4 p0 = pn[0], p1 = pn[1], p2 = pn[2], p3 = pn[3], p4 = pn[4]; \
    float dot = 0.f; \
    dot += p0.x * a0.x; dot += p0.y * a0.y; dot += p0.z * a0.z; dot += p0.w * a0.w; \
    dot += p1.x * a1.x; dot += p1.y * a1.y; dot += p1.z * a1.z; dot += p1.w * a1.w; \
    dot += p2.x * a2.x; dot += p2.y * a2.y; dot += p2.z * a2.z; dot += p2.w * a2.w; \
    dot += p3.x * a3.x; dot += p3.y * a3.y; dot += p3.z * a3.z; dot += p3.w * a3.w; \
    dot += p4.x * a4.x; dot += p4.y * a4.y; dot += p4.z * a4.z; \
    KV = lsn.y - dot + lzc; }
    SLOTK(0, kv0) SLOTK(1, kv1) SLOTK(2, kv2) SLOTK(3, kv3)
    SLOTK(4, kv4) SLOTK(5, kv5) SLOTK(6, kv6) SLOTK(7, kv7)
#undef SLOTK
    // max/sum trees: exact R11/R13/R14-validated pairing
    float kmax = fmaxf(fmaxf(fmaxf(kv0, kv1), fmaxf(kv2, kv3)),
                       fmaxf(fmaxf(kv4, kv5), fmaxf(kv6, kv7)));
    float s01 = __expf(kv0 - kmax) + __expf(kv1 - kmax);
    float s23 = __expf(kv2 - kmax) + __expf(kv3 - kmax);
    float s45 = __expf(kv4 - kmax) + __expf(kv5 - kmax);
    float s67 = __expf(kv6 - kmax) + __expf(kv7 - kmax);
    float ssum = (s01 + s23) + (s45 + s67);
    float kll = label == 0 ? kv0 : label == 1 ? kv1 : label == 2 ? kv2 : label == 3 ? kv3
              : label == 4 ? kv4 : label == 5 ? kv5 : label == 6 ? kv6 : kv7;
    acc += kmax + __logf(ssum) - kll;
  }
  block_reduce_add_w(acc, out, 4);
}

// ---------------- launch -----------------------------------------------------
extern "C" void kernel_launch(void* const* d_in, const int* in_sizes, int n_in,
                              void* d_out, int out_size, void* d_ws, size_t ws_size,
                              hipStream_t stream) {
  const float* sl  = (const float*)d_in[0];
  const int*   tgt = (const int*)d_in[1];
  float* out = (float*)d_out;

  int*    hist    = (int*)d_ws;                // 257 ints (zeroed by k_rowdt)
  float*  eps_sel = (float*)d_ws + 320;
  float2* LS      = (float2*)((float*)d_ws + 512);      // (logZ, S) per pixel
  float*  kl_map  = (float*)d_ws + 512 + 2 * NPIX_;
  int*    dist    = (int*)(kl_map + NPIX_);
  int*    Rt      = dist + NPIX_;
  float*  X       = (float*)(Rt + NPIX_);      // [NPIX][REC_] logits records
  float*  P       = X + (size_t)NPIX_ * REC_;  // [NPIX][REC_] softmax records

  k_rowdt<<<B_ * H_, W_, 0, stream>>>(tgt, Rt, hist, out);
  k_soft<<<NPIX_ / 2 / 256, 256, 0, stream>>>(sl, tgt, LS, kl_map, X, P, hist, out);
  k_coldt<<<B_ * W_, H_, 0, stream>>>(Rt, dist, hist, eps_sel);
  k_maskce<<<dim3(W_ / 16, H_ / 16, B_), 256, 0, stream>>>(X, P, LS, kl_map, dist, eps_sel, out);
}

// Round 16
// 132.046 us; speedup vs baseline: 1.0362x; 1.0362x over previous
//
#include <hip/hip_runtime.h>
#include <math.h>

#define B_    4
#define C_    19
#define H_    320
#define W_    320
#define HW_   (H_*W_)
#define CHW_  (C_*HW_)
#define NPIX_ (B_*HW_)
#define NEPS_ 256
#define BIGI_ (1<<20)
#define INF_  0x3fffffff
#define IGN_  255
#define REC_  20          // padded record stride (floats)

// Compile-time exact replica of the reference eps chain: e0=1e-5f, e_{k+1}=e_k*1.2f
struct EpsTab { float v[NEPS_]; };
static constexpr EpsTab make_eps() {
  EpsTab t{}; float e = 1e-5f;
  for (int k = 0; k < NEPS_; ++k) { t.v[k] = e; e = e * 1.2f; }
  return t;
}
__device__ __constant__ EpsTab EPS = make_eps();

// ---------------- reduction helper (nw full waves) ---------------------------
__device__ __forceinline__ void block_reduce_add_w(float v, float* out, int nw) {
  #pragma unroll
  for (int o = 32; o > 0; o >>= 1) v += __shfl_down(v, o);
  __shared__ float shr[8];
  int lane = threadIdx.x & 63, wid = threadIdx.x >> 6;
  if (lane == 0) shr[wid] = v;
  __syncthreads();
  if (threadIdx.x == 0) {
    float s = 0.f;
    for (int w = 0; w < nw; ++w) s += shr[w];
    atomicAdd(out, s);
  }
}

__device__ __forceinline__ int eps_bin(float kl, const float* et) {
  // #{k : e_k < kl}, log2 guess + exact correction (identical compares to ref)
  if (!(kl > 1e-5f)) return 0;
  int g = (int)((__log2f(kl) + 16.6096404f) * 3.8017840f);
  g = min(max(g, 0), NEPS_ - 1);
  while (g < NEPS_ && et[g] < kl) ++g;
  while (g > 0 && !(et[g - 1] < kl)) --g;
  return g;
}

// ---------------- K1: row distance transform + workspace init ---------------
__global__ __launch_bounds__(320) void k_rowdt(const int* __restrict__ tgt, int* __restrict__ Rt,
                                               int* __restrict__ hist, float* __restrict__ out) {
  int bid = blockIdx.x;                  // b*H_ + i
  int b = bid / H_, i = bid - b * H_;
  int j = threadIdx.x, lane = j & 63, wv = j >> 6;
  if (bid == 0) {
    if (j < 257) hist[j] = 0;
    if (j == 319) out[0] = 0.f;
  }
  bool hd = (i < H_ - 1);
  const int* trow = tgt + b * HW_ + i * W_;
  int t0 = trow[j];
  int t1 = hd ? trow[W_ + j] : t0;
  int t0r = (j < W_ - 1) ? trow[j + 1] : t0;
  bool bnd = (t0 == IGN_) || (t1 != t0) || (t0r != t0);
  int s = bnd ? 0 : BIGI_;
  int a = s - j, c = s + j;
  #pragma unroll
  for (int o = 1; o < 64; o <<= 1) {
    int v = __shfl_up(a, o);
    if (lane >= o) a = min(a, v);
    int w = __shfl_down(c, o);
    if (lane + o < 64) c = min(c, w);
  }
  __shared__ int wa[5], wc[5];
  if (lane == 63) wa[wv] = a;
  if (lane == 0)  wc[wv] = c;
  __syncthreads();
  #pragma unroll
  for (int w = 0; w < 5; ++w) {
    if (w < wv) a = min(a, wa[w]);
    if (w > wv) c = min(c, wc[w]);
  }
  Rt[(b * W_ + j) * H_ + i] = min(a + j, c - j);   // transposed store
}

// ---------------- K0: per-PAIR softmax/KL (f2b) + LDS-coalesced X/P stores --
// EXACT R14 version (measured best kernel: total 134.1us; absmax 0.0).
__global__ __launch_bounds__(256) void k_soft(const float* __restrict__ sl, const int* __restrict__ tgt,
                                              float2* __restrict__ LS, float* __restrict__ kl_map,
                                              float* __restrict__ X, float* __restrict__ P,
                                              int* __restrict__ hist, float* __restrict__ out) {
  int tid = threadIdx.x;
  int t = blockIdx.x * 256 + tid;                // pair index, 0..NPIX_/2-1
  int b = t / (HW_ / 2), q = t - b * (HW_ / 2);
  int p = q * 2;                                 // pixel base (j even)
  int i = p / W_, j = p - i * W_;
  bool hd = (i < H_ - 1);
  bool hr1 = (j + 2 < W_);                       // pixel1 has a right neighbor
  __shared__ float et[NEPS_];
  __shared__ int sh[257];
  __shared__ float RS[256][41];                  // record staging (X, then P)
  et[tid] = EPS.v[tid];
  sh[tid] = 0;
  if (tid == 0) sh[256] = 0;

  const float* base = sl + (size_t)b * CHW_ + p;
  int2 t2 = *(const int2*)(tgt + b * HW_ + p);

  float x0s[C_], x1s[C_];                        // own logits stash (static idx)
  float se0=0.f,se1=0.f, E0=0.f,E1=0.f;
  float dD0=0.f,dD1=0.f, sB0=0.f,sB1=0.f;
  float dR0=0.f,dR1=0.f, sR1=0.f;
  float xt0=0.f,xt1=0.f;
  #pragma unroll
  for (int c0 = 0; c0 < C_; c0 += 5) {
    const int NB = (c0 + 5 <= C_) ? 5 : (C_ - c0);
    float2 xo[5], xd[5];
    float  xr[5];
    #pragma unroll
    for (int k = 0; k < NB; ++k) {
      const float* pc = base + (c0 + k) * HW_;
      xo[k] = *(const float2*)pc;
      xd[k] = hd ? *(const float2*)(pc + W_) : make_float2(0.f, 0.f);
      xr[k] = hr1 ? pc[2] : 0.f;
    }
    #pragma unroll
    for (int k = 0; k < NB; ++k) {
      int c = c0 + k;
      x0s[c] = xo[k].x; x1s[c] = xo[k].y;
      float e0 = __expf(xo[k].x), e1 = __expf(xo[k].y);
      se0 += e0; E0 += e0 * xo[k].x;
      se1 += e1; E1 += e1 * xo[k].y;
      dD0 += e0 * xd[k].x; dD1 += e1 * xd[k].y;
      sB0 += __expf(xd[k].x); sB1 += __expf(xd[k].y);
      dR0 += e0 * xo[k].y; dR1 += e1 * xr[k];
      sR1 += __expf(xr[k]);
      if (c == t2.x) xt0 = xo[k].x;
      if (c == t2.y) xt1 = xo[k].y;
    }
  }
  float lz0 = __logf(se0), lz1 = __logf(se1);
  float Sv0 = E0 / se0 - lz0, Sv1 = E1 / se1 - lz1;
  float nll = ((t2.x != IGN_) ? (lz0 - xt0) : 0.f) + ((t2.y != IGN_) ? (lz1 - xt1) : 0.f);
  float kl0 = hd ? (Sv0 - dD0 / se0 + __logf(sB0)) : 0.f;
  float kl1 = hd ? (Sv1 - dD1 / se1 + __logf(sB1)) : 0.f;
  kl0 += Sv0 - dR0 / se0 + lz1;
  if (hr1) kl1 += Sv1 - dR1 / se1 + __logf(sR1);

  // ---- X records via LDS coalescing ----
  #pragma unroll
  for (int c = 0; c < C_; ++c) { RS[tid][c] = x0s[c]; RS[tid][20 + c] = x1s[c]; }
  RS[tid][19] = 0.f; RS[tid][40] = 0.f;
  RS[tid][39] = 0.f;
  __syncthreads();
  {
    float* xb = X + (size_t)blockIdx.x * (256 * 2 * REC_);
    #pragma unroll
    for (int r = 0; r < 10; ++r) {
      int f4 = r * 256 + tid;                    // 0..2559
      int rec = f4 / 10, e0 = (f4 - rec * 10) * 4;
      float4 v = make_float4(RS[rec][e0], RS[rec][e0 + 1], RS[rec][e0 + 2], RS[rec][e0 + 3]);
      *(float4*)(xb + (size_t)f4 * 4) = v;       // rec*40+e0 == f4*4: linear, coalesced
    }
  }
  __syncthreads();
  // ---- P records via LDS coalescing (exp computed straight into LDS) ----
  #pragma unroll
  for (int c = 0; c < C_; ++c) {
    RS[tid][c]      = __expf(x0s[c] - lz0);      // same input bits as R13 -> same output
    RS[tid][20 + c] = __expf(x1s[c] - lz1);
  }
  RS[tid][19] = 0.f; RS[tid][39] = 0.f;
  __syncthreads();
  {
    float* pb = P + (size_t)blockIdx.x * (256 * 2 * REC_);
    #pragma unroll
    for (int r = 0; r < 10; ++r) {
      int f4 = r * 256 + tid;
      int rec = f4 / 10, e0 = (f4 - rec * 10) * 4;
      float4 v = make_float4(RS[rec][e0], RS[rec][e0 + 1], RS[rec][e0 + 2], RS[rec][e0 + 3]);
      *(float4*)(pb + (size_t)f4 * 4) = v;
    }
  }

  int gp = b * HW_ + p;
  LS[gp]     = make_float2(lz0, Sv0);
  LS[gp + 1] = make_float2(lz1, Sv1);
  *(float2*)(kl_map + gp) = make_float2(kl0, kl1);
  __syncthreads();                       // et/sh init + staging done
  atomicAdd(&sh[eps_bin(kl0, et)], 1);
  atomicAdd(&sh[eps_bin(kl1, et)], 1);
  __syncthreads();
  if (sh[tid]) atomicAdd(&hist[tid], sh[tid]);
  if (tid == 0 && sh[256]) atomicAdd(&hist[256], sh[256]);
  block_reduce_add_w(nll, out, 4);
}

// ---------------- K2: column combine + (block 0) eps selection --------------
__global__ __launch_bounds__(H_) void k_coldt(const int* __restrict__ Rt, int* __restrict__ dist,
                                              const int* __restrict__ hist, float* __restrict__ eps_sel) {
  int b = blockIdx.x / W_, j = blockIdx.x % W_, tid = threadIdx.x;
  __shared__ int lev[9][H_];
  lev[0][tid] = Rt[(b * W_ + j) * H_ + tid];
  int Ri = lev[0][tid];
  for (int l = 1; l <= 8; ++l) {
    int half = 1 << (l - 1);
    __syncthreads();
    int other = (tid + half < H_) ? lev[l - 1][tid + half] : INF_;
    lev[l][tid] = min(lev[l - 1][tid], other);
  }
  __syncthreads();
  int i0 = tid;
  auto feas = [&](int dd) -> bool {
    int lo = max(0, i0 - dd), hi = min(H_ - 1, i0 + dd);
    int len = hi - lo + 1;
    int l = 31 - __clz(len);
    int m = min(lev[l][lo], lev[l][hi - (1 << l) + 1]);
    return m <= dd;
  };
  int d;
  int hi = min(Ri, 512);                 // d <= R[i0]
  if (!feas(hi)) d = B_ + 1 + H_ + W_;   // no seed in image
  else {
    int lo = 0;
    while (lo < hi) { int mid = (lo + hi) >> 1; if (feas(mid)) hi = mid; else lo = mid + 1; }
    d = lo;
  }
  dist[(b * H_ + i0) * W_ + j] = d;
  // block 0: eps via suffix scan of hist (bins 1..256)
  if (blockIdx.x == 0) {
    __shared__ int g[256];
    __shared__ int bestk;
    if (tid < 256) g[tid] = hist[tid + 1];
    if (tid == 0) bestk = NEPS_ - 1;
    __syncthreads();
    #pragma unroll
    for (int ofs = 1; ofs < 256; ofs <<= 1) {
      int v = 0;
      if (tid < 256) v = g[tid] + ((tid + ofs < 256) ? g[tid + ofs] : 0);
      __syncthreads();
      if (tid < 256) g[tid] = v;
      __syncthreads();
    }
    if (tid < 256 && g[tid] <= 5120) atomicMin(&bestk, tid);
    __syncthreads();
    if (tid == 0) eps_sel[0] = EPS.v[bestk];
  }
}

// ---------------- K3: mask+direction+dterm + CE from X/P records ------------
// EXACT R14 version (part of the measured-best 134.1us configuration).
__global__ __launch_bounds__(256) void k_maskce(const float* __restrict__ X, const float* __restrict__ P,
                                                const float2* __restrict__ LS, const float* __restrict__ kl_map,
                                                const int* __restrict__ dist, const float* __restrict__ eps_sel,
                                                float* __restrict__ out) {
  const int nx9[9] = {1,-1,0,0,-1,1,-1,1,0};
  const int ny9[9] = {0,0,-1,1,1,1,-1,-1,0};
  int tid = threadIdx.x;
  int b = blockIdx.z;
  int i0 = blockIdx.y * 16, j0 = blockIdx.x * 16;
  float eps = eps_sel[0];
  __shared__ float kt[18][19];
  __shared__ int   dt_[18][19];
  for (int e = tid; e < 324; e += 256) {
    int r = e / 18, cc = e - r * 18;
    int gi = i0 - 1 + r, gj = j0 - 1 + cc;
    bool in = (gi >= 0 && gi < H_ && gj >= 0 && gj < W_);
    int gidx = (b * H_ + gi) * W_ + gj;
    kt[r][cc]  = in ? kl_map[gidx] : -1e30f;
    dt_[r][cc] = in ? dist[gidx] : 100000;
  }
  __syncthreads();
  int li = tid >> 4, lj = tid & 15;
  bool mask = false;
  #pragma unroll
  for (int dr = 0; dr < 3; ++dr)
    #pragma unroll
    for (int dc = 0; dc < 3; ++dc)
      mask |= (kt[li + dr][lj + dc] > eps);
  int best = INF_, dir = 0;
  #pragma unroll
  for (int k = 0; k < 9; ++k) {
    int r = dt_[li + 1 + nx9[k]][lj + 1 + ny9[k]];
    if (r < best) { best = r; dir = k; }
  }
  bool valid = mask && (dir != 8);
  float acc = 0.f;
  if (valid) {
    int i = i0 + li, j = j0 + lj;
    acc = fminf((float)dt_[li + 1][lj + 1], 20.f) * (1.f / 20.f);
    int label = min(dir, 7);
    int gp = b * HW_ + i * W_ + j;
    float lzc = LS[gp].x;
    const float4* xo = (const float4*)(X + (size_t)gp * REC_);
    float4 a0 = xo[0], a1 = xo[1], a2 = xo[2], a3 = xo[3], a4 = xo[4];
    float kv0, kv1, kv2, kv3, kv4, kv5, kv6, kv7;
#define SLOTK(K, KV) { \
    int ic = i + nx9[K]; ic = ic < 0 ? 0 : (ic > H_ - 1 ? H_ - 1 : ic); \
    int jc = j + ny9[K]; jc = jc < 0 ? 0 : (jc > W_ - 1 ? W_ - 1 : jc); \
    int gn = b * HW_ + ic * W_ + jc; \
    float2 lsn = LS[gn]; \
    const float4* pn = (const float4*)(P + (size_t)gn * REC_); \
    float4 p0 = pn[0], p1 = pn[1], p2 = pn[2], p3 = pn[3], p4 = pn[4]; \
    float dot = 0.f; \
    dot += p0.x * a0.x; dot += p0.y * a0.y; dot += p0.z * a0.z; dot += p0.w * a0.w; \
    dot += p1.x * a1.x; dot += p1.y * a1.y; dot += p1.z * a1.z; dot += p1.w * a1.w; \
    dot += p2.x * a2.x; dot += p2.y * a2.y; dot += p2.z * a2.z; dot += p2.w * a2.w; \
    dot += p3.x * a3.x; dot += p3.y * a3.y; dot += p3.z * a3.z; dot += p3.w * a3.w; \
    dot += p4.x * a4.x; dot += p4.y * a4.y; dot += p4.z * a4.z; \
    KV = lsn.y - dot + lzc; }
    SLOTK(0, kv0) SLOTK(1, kv1) SLOTK(2, kv2) SLOTK(3, kv3)
    SLOTK(4, kv4) SLOTK(5, kv5) SLOTK(6, kv6) SLOTK(7, kv7)
#undef SLOTK
    // max/sum trees: exact R11/R13-validated pairing
    float kmax = fmaxf(fmaxf(fmaxf(kv0, kv1), fmaxf(kv2, kv3)),
                       fmaxf(fmaxf(kv4, kv5), fmaxf(kv6, kv7)));
    float s01 = __expf(kv0 - kmax) + __expf(kv1 - kmax);
    float s23 = __expf(kv2 - kmax) + __expf(kv3 - kmax);
    float s45 = __expf(kv4 - kmax) + __expf(kv5 - kmax);
    float s67 = __expf(kv6 - kmax) + __expf(kv7 - kmax);
    float ssum = (s01 + s23) + (s45 + s67);
    float kll = label == 0 ? kv0 : label == 1 ? kv1 : label == 2 ? kv2 : label == 3 ? kv3
              : label == 4 ? kv4 : label == 5 ? kv5 : label == 6 ? kv6 : kv7;
    acc += kmax + __logf(ssum) - kll;
  }
  block_reduce_add_w(acc, out, 4);
}

// ---------------- launch -----------------------------------------------------
extern "C" void kernel_launch(void* const* d_in, const int* in_sizes, int n_in,
                              void* d_out, int out_size, void* d_ws, size_t ws_size,
                              hipStream_t stream) {
  const float* sl  = (const float*)d_in[0];
  const int*   tgt = (const int*)d_in[1];
  float* out = (float*)d_out;

  int*    hist    = (int*)d_ws;                // 257 ints (zeroed by k_rowdt)
  float*  eps_sel = (float*)d_ws + 320;
  float2* LS      = (float2*)((float*)d_ws + 512);      // (logZ, S) per pixel
  float*  kl_map  = (float*)d_ws + 512 + 2 * NPIX_;
  int*    dist    = (int*)(kl_map + NPIX_);
  int*    Rt      = dist + NPIX_;
  float*  X       = (float*)(Rt + NPIX_);      // [NPIX][REC_] logits records
  float*  P       = X + (size_t)NPIX_ * REC_;  // [NPIX][REC_] softmax records

  k_rowdt<<<B_ * H_, W_, 0, stream>>>(tgt, Rt, hist, out);
  k_soft<<<NPIX_ / 2 / 256, 256, 0, stream>>>(sl, tgt, LS, kl_map, X, P, hist, out);
  k_coldt<<<B_ * W_, H_, 0, stream>>>(Rt, dist, hist, eps_sel);
  k_maskce<<<dim3(W_ / 16, H_ / 16, B_), 256, 0, stream>>>(X, P, LS, kl_map, dist, eps_sel, out);
}